// Round 13
// baseline (114.286 us; speedup 1.0000x reference)
//
#include <hip/hip_runtime.h>
#include <hip/hip_cooperative_groups.h>

namespace cg = cooperative_groups;

#define N_NODES 10000
#define N_EDGES 640000
#define D 128
#define NSHARD 8
#define SLOTS 64                       // 128 B = one cache line per (node,shard)
#define NODE_STRIDE (NSHARD * SLOTS)   // 512 ushorts = 1 KB per node

typedef __attribute__((ext_vector_type(8))) short bf16x8;
typedef __attribute__((ext_vector_type(4))) float f32x4;

// ws layout (int units):
//   edge_src : 10000*512 ushort = 2,560,000 ints (10.24 MB)
//   cnt      : 8 x 10000        =    80,000 ints
//   y        : 1.28M bf16       =   640,000 ints
#define WS_EDGESRC 0
#define WS_CNT     2560000
#define WS_Y       2640000

#define GEMM_BLOCKS 157                // ceil(10000/64)
#define SCAT_UNITS  2500               // 2500 x 256 = 640000 edges
#define AGG_UNITS   2500               // 2500 x 4 nodes = 10000
#define WLD 136

__device__ __forceinline__ unsigned bf16_rtne(unsigned u) {
    return (u + 0x7fffu + ((u >> 16) & 1u)) >> 16;
}
__device__ __forceinline__ float blo(unsigned v) { return __uint_as_float(v << 16); }
__device__ __forceinline__ float bhi(unsigned v) { return __uint_as_float(v & 0xffff0000u); }

// ===========================================================================
// Reusable device bodies (shared by coop mega-kernel and fallback kernels)
// ===========================================================================
__device__ __forceinline__ void stage_W_lds(const float* __restrict__ W,
                                            unsigned short* Wl, int t) {
    const uint2* W2 = (const uint2*)W;
    #pragma unroll
    for (int u = t; u < 8192; u += 256) {
        uint2 w = W2[u];
        unsigned p = bf16_rtne(w.x) | (bf16_rtne(w.y) << 16);
        *(unsigned*)&Wl[(u >> 6) * WLD + (u & 63) * 2] = p;
    }
}

__device__ __forceinline__ void gemm_body(const float* __restrict__ x,
                                          const unsigned short* Wl,
                                          unsigned short* __restrict__ y,
                                          int blk, int t) {
    int wave = t >> 6;
    int lane = t & 63;
    int l16  = lane & 15;
    int quad = lane >> 4;

    int m0 = blk * 64 + wave * 16;
    int anode = m0 + l16;
    if (anode >= N_NODES) anode = N_NODES - 1;

    f32x4 acc[8];
    #pragma unroll
    for (int i = 0; i < 8; ++i) acc[i] = (f32x4){0.f, 0.f, 0.f, 0.f};

    #pragma unroll
    for (int ks = 0; ks < 4; ++ks) {
        const uint4* ap = (const uint4*)(x + anode * D + ks * 32 + quad * 8);
        uint4 a0 = ap[0];
        uint4 a1 = ap[1];
        union { unsigned u[4]; bf16x8 v; } af;
        af.u[0] = bf16_rtne(a0.x) | (bf16_rtne(a0.y) << 16);
        af.u[1] = bf16_rtne(a0.z) | (bf16_rtne(a0.w) << 16);
        af.u[2] = bf16_rtne(a1.x) | (bf16_rtne(a1.y) << 16);
        af.u[3] = bf16_rtne(a1.z) | (bf16_rtne(a1.w) << 16);
        #pragma unroll
        for (int ot = 0; ot < 8; ++ot) {
            bf16x8 bf = *(const bf16x8*)&Wl[(ot * 16 + l16) * WLD + ks * 32 + quad * 8];
            acc[ot] = __builtin_amdgcn_mfma_f32_16x16x32_bf16(af.v, bf, acc[ot], 0, 0, 0);
        }
    }

    #pragma unroll
    for (int ot = 0; ot < 8; ++ot) {
        int o = ot * 16 + l16;
        #pragma unroll
        for (int r = 0; r < 4; ++r) {
            int node = m0 + quad * 4 + r;
            if (node < N_NODES)
                y[node * D + o] = (unsigned short)bf16_rtne(__float_as_uint(acc[ot][r]));
        }
    }
}

__device__ __forceinline__ void scatter_unit(const int* __restrict__ src,
                                             const int* __restrict__ dst,
                                             int* __restrict__ cnt,
                                             unsigned short* __restrict__ edge_src,
                                             int u, int t) {
    int i = u * 256 + t;
    int s = src[i];
    int d = dst[i];
    int sh = u & (NSHARD - 1);
    int p = atomicAdd(&cnt[sh * N_NODES + d], 1);
    if (p < SLOTS)
        edge_src[d * NODE_STRIDE + sh * SLOTS + p] = (unsigned short)s;
}

__device__ __forceinline__ void agg_unit(const uint4* __restrict__ y4,
                                         const unsigned short* __restrict__ edge_src,
                                         const int* __restrict__ cnt,
                                         const float* __restrict__ b,
                                         float4* __restrict__ out4,
                                         float* part, int unit, int t) {
    int qw = t >> 4;                 // 0..15
    int l  = t & 15;                 // col group (8 bf16 = 32 B fp32 out)
    int m  = qw & 3;                 // node slot 0..3
    int p  = qw >> 2;                // shard-pair 0..3
    int n  = unit * 4 + m;

    float acc[8];
    #pragma unroll
    for (int i = 0; i < 8; ++i) acc[i] = 0.f;

    int cA = cnt[p * N_NODES + n];
    int cB = cnt[(p + 4) * N_NODES + n];
    if (cA > SLOTS) cA = SLOTS;
    if (cB > SLOTS) cB = SLOTS;
    const unsigned short* segA = edge_src + n * NODE_STRIDE + p * SLOTS;
    const unsigned short* segB = edge_src + n * NODE_STRIDE + (p + 4) * SLOTS;
    int nb = cA > cB ? cA : cB;

    for (int j = 0; j < nb; j += 8) {
        uint4 siA = *(const uint4*)(segA + j);
        uint4 siB = *(const uint4*)(segB + j);
        unsigned iA[8], iB[8];
        iA[0] = siA.x & 0xffffu; iA[1] = siA.x >> 16;
        iA[2] = siA.y & 0xffffu; iA[3] = siA.y >> 16;
        iA[4] = siA.z & 0xffffu; iA[5] = siA.z >> 16;
        iA[6] = siA.w & 0xffffu; iA[7] = siA.w >> 16;
        iB[0] = siB.x & 0xffffu; iB[1] = siB.x >> 16;
        iB[2] = siB.y & 0xffffu; iB[3] = siB.y >> 16;
        iB[4] = siB.z & 0xffffu; iB[5] = siB.z >> 16;
        iB[6] = siB.w & 0xffffu; iB[7] = siB.w >> 16;
        #pragma unroll
        for (int u = 0; u < 8; ++u) {
            unsigned mA = (j + u < cA) ? 0xffffffffu : 0u;
            unsigned mB = (j + u < cB) ? 0xffffffffu : 0u;
            uint4 vA = y4[iA[u] * 16 + l];
            uint4 vB = y4[iB[u] * 16 + l];
            vA.x &= mA; vA.y &= mA; vA.z &= mA; vA.w &= mA;
            vB.x &= mB; vB.y &= mB; vB.z &= mB; vB.w &= mB;
            acc[0] += blo(vA.x) + blo(vB.x); acc[1] += bhi(vA.x) + bhi(vB.x);
            acc[2] += blo(vA.y) + blo(vB.y); acc[3] += bhi(vA.y) + bhi(vB.y);
            acc[4] += blo(vA.z) + blo(vB.z); acc[5] += bhi(vA.z) + bhi(vB.z);
            acc[6] += blo(vA.w) + blo(vB.w); acc[7] += bhi(vA.w) + bhi(vB.w);
        }
    }

    __syncthreads();                          // part[] safe to overwrite
    {
        float* pr = &part[(qw * 16 + l) * 9]; // stride 9: conflict-free
        #pragma unroll
        for (int k = 0; k < 8; ++k) pr[k] = acc[k];
    }
    __syncthreads();

    if (p == 0) {
        #pragma unroll
        for (int p2 = 1; p2 < 4; ++p2) {
            const float* pr = &part[(((p2 << 2) | m) * 16 + l) * 9];
            #pragma unroll
            for (int k = 0; k < 8; ++k) acc[k] += pr[k];
        }
        const float4* b4 = (const float4*)b;
        float4 b0 = b4[l * 2], b1 = b4[l * 2 + 1];
        out4[n * 32 + l * 2]     = make_float4(acc[0] + b0.x, acc[1] + b0.y,
                                               acc[2] + b0.z, acc[3] + b0.w);
        out4[n * 32 + l * 2 + 1] = make_float4(acc[4] + b1.x, acc[5] + b1.y,
                                               acc[6] + b1.z, acc[7] + b1.w);
    }
}

// ===========================================================================
// Cooperative mega-kernel (grid-stride in every phase: correct for ANY grid
// size >= 158). LDS 43 KB -> occupancy >= 3 blocks/CU; launched at
// min(queried_occ, 3) * 256 blocks to stay safely under the coop limit.
// ===========================================================================
__global__ __launch_bounds__(256) void mega_kernel(
    const float* __restrict__ x,
    const float* __restrict__ W,
    const int* __restrict__ src,
    const int* __restrict__ dst,
    const float* __restrict__ b,
    int* __restrict__ cnt,
    unsigned short* __restrict__ edge_src,
    unsigned short* __restrict__ y,
    float4* __restrict__ out4) {
    __shared__ __align__(16) unsigned short Wl[D * WLD];   // 34.8 KB
    __shared__ float part[16 * 16 * 9];                    //  9.2 KB

    cg::grid_group grid = cg::this_grid();
    int t = threadIdx.x;
    int blk = blockIdx.x;
    int nblk = gridDim.x;

    // ---- phase 0: zero cnt (grid-stride); gemm blocks stage W -> LDS ----
    for (int i = blk * 256 + t; i < NSHARD * N_NODES; i += nblk * 256) cnt[i] = 0;
    if (blk < GEMM_BLOCKS) stage_W_lds(W, Wl, t);
    __threadfence();
    grid.sync();

    // ---- phase 1: gemm (blocks < 157) || scatter (rest, grid-stride) ----
    if (blk < GEMM_BLOCKS) {
        gemm_body(x, Wl, y, blk, t);
    } else {
        for (int u = blk - GEMM_BLOCKS; u < SCAT_UNITS; u += nblk - GEMM_BLOCKS)
            scatter_unit(src, dst, cnt, edge_src, u, t);
    }
    __threadfence();
    grid.sync();

    // ---- phase 2: aggregation (all blocks, grid-stride) ----
    const uint4* y4 = (const uint4*)y;
    for (int unit = blk; unit < AGG_UNITS; unit += nblk)
        agg_unit(y4, edge_src, cnt, b, out4, part, unit, t);
}

// ===========================================================================
// Fallback path (R11-identical 3-dispatch pipeline) in case coop launch errors
// ===========================================================================
__global__ __launch_bounds__(256) void fused_gemm_scatter_kernel(
    const float* __restrict__ x,
    const float* __restrict__ W,
    const int* __restrict__ src,
    const int* __restrict__ dst,
    int* __restrict__ cnt,
    unsigned short* __restrict__ edge_src,
    unsigned short* __restrict__ y) {
    __shared__ __align__(16) unsigned short Wl[D * WLD];
    int t = threadIdx.x;
    if (blockIdx.x >= GEMM_BLOCKS) {
        scatter_unit(src, dst, cnt, edge_src, blockIdx.x - GEMM_BLOCKS, t);
        return;
    }
    stage_W_lds(W, Wl, t);
    __syncthreads();
    gemm_body(x, Wl, y, blockIdx.x, t);
}

__global__ __launch_bounds__(256) void agg_kernel(
    const uint4* __restrict__ y4,
    const unsigned short* __restrict__ edge_src,
    const int* __restrict__ cnt,
    const float* __restrict__ b,
    float4* __restrict__ out4) {
    __shared__ float part[16 * 16 * 9];
    agg_unit(y4, edge_src, cnt, b, out4, part, blockIdx.x, threadIdx.x);
}

// ---------------------------------------------------------------------------
extern "C" void kernel_launch(void* const* d_in, const int* in_sizes, int n_in,
                              void* d_out, int out_size, void* d_ws, size_t ws_size,
                              hipStream_t stream) {
    const float* x   = (const float*)d_in[0];
    const int*   src = (const int*)  d_in[1];
    const int*   dst = (const int*)  d_in[2];
    const float* W   = (const float*)d_in[3];
    const float* b   = (const float*)d_in[4];
    float4* out4 = (float4*)d_out;

    int* wsI = (int*)d_ws;
    unsigned short* edge_src = (unsigned short*)(wsI + WS_EDGESRC);
    int* cnt = wsI + WS_CNT;
    unsigned short* y = (unsigned short*)(wsI + WS_Y);

    // Deterministic grid sizing: query co-residency, cap at 3 blocks/CU to
    // stay safely below the exact cooperative-launch limit (R12 failed at
    // exactly the theoretical max).
    int occ = 0;
    hipError_t qe = hipOccupancyMaxActiveBlocksPerMultiprocessor(&occ, mega_kernel, 256, 0);
    if (qe != hipSuccess) occ = 0;
    if (occ > 3) occ = 3;
    int grid = occ * 256;

    hipError_t le = hipErrorUnknown;
    if (grid >= 2 * GEMM_BLOCKS) {
        void* args[] = {(void*)&x, (void*)&W, (void*)&src, (void*)&dst, (void*)&b,
                        (void*)&cnt, (void*)&edge_src, (void*)&y, (void*)&out4};
        le = hipLaunchCooperativeKernel((void*)mega_kernel, dim3(grid), dim3(256),
                                        args, 0, stream);
    }

    if (le != hipSuccess) {
        // Fallback: R11 3-dispatch pipeline (known-good, ~114 us)
        hipMemsetAsync(cnt, 0, NSHARD * N_NODES * sizeof(int), stream);
        fused_gemm_scatter_kernel<<<GEMM_BLOCKS + SCAT_UNITS, 256, 0, stream>>>(
            x, W, src, dst, cnt, edge_src, y);
        agg_kernel<<<AGG_UNITS, 256, 0, stream>>>(
            (const uint4*)y, edge_src, cnt, b, out4);
    }
}